// Round 4
// baseline (214.252 us; speedup 1.0000x reference)
//
#include <hip/hip_runtime.h>

#define NN 10000
#define NE 640000
#define D  128
#define PAD_SHIFT 8              // 256 slots per node; P(deg>=256 | mean 64) < 1e-20

// ---- zero the per-node counters ----------------------------------------

__global__ __launch_bounds__(256) void zero_kernel(int* __restrict__ p, int n) {
    int i = blockIdx.x * 256 + threadIdx.x;
    if (i < n) p[i] = 0;
}

// ---- fused count + scatter into padded CSR (one pass over edges) --------

__global__ __launch_bounds__(256) void count_scatter_kernel(const int* __restrict__ ei,
                                                            const float* __restrict__ ew,
                                                            int* __restrict__ cnt,
                                                            int2* __restrict__ epack) {
    int e = blockIdx.x * 256 + threadIdx.x;
    if (e < NE) {
        int   r = ei[e];             // source
        int   c = ei[NE + e];        // target
        float w = ew[e];
        int rank = atomicAdd(&cnt[c], 1);
        int2 v;
        v.x = r;
        v.y = __float_as_int(w);
        epack[((size_t)c << PAD_SHIFT) + rank] = v;
    }
}

// ---- deg -> dinv from padded CSR, wave per node -------------------------

__global__ __launch_bounds__(256) void degdinv_kernel(const int* __restrict__ cnt,
                                                      const int2* __restrict__ epack,
                                                      float* __restrict__ dinv) {
    int node = blockIdx.x * 4 + (threadIdx.x >> 6);
    if (node >= NN) return;
    int lane = threadIdx.x & 63;
    int m = cnt[node];
    const int2* base = epack + ((size_t)node << PAD_SHIFT);
    float s = 0.0f;
    for (int j = lane; j < m; j += 64) s += __int_as_float(base[j].y);
#pragma unroll
    for (int off = 32; off; off >>= 1) s += __shfl_down(s, off);
    if (lane == 0) dinv[node] = rsqrtf(s + 1.0f);      // +1 = self loop
}

// ---- dense H = X @ W ----------------------------------------------------

__global__ __launch_bounds__(128) void gemm_kernel(const float* __restrict__ X,
                                                   const float* __restrict__ W,
                                                   float* __restrict__ H) {
    __shared__ float xs[16][D];
    int r0 = blockIdx.x * 16;
    int d  = threadIdx.x;
#pragma unroll
    for (int r = 0; r < 16; ++r) {
        int rr = r0 + r;
        xs[r][d] = (rr < NN) ? X[rr * D + d] : 0.0f;
    }
    __syncthreads();
    float acc[16];
#pragma unroll
    for (int r = 0; r < 16; ++r) acc[r] = 0.0f;
    for (int k = 0; k < D; k += 4) {
        float w0 = W[(k + 0) * D + d];
        float w1 = W[(k + 1) * D + d];
        float w2 = W[(k + 2) * D + d];
        float w3 = W[(k + 3) * D + d];
#pragma unroll
        for (int r = 0; r < 16; ++r) {
            float4 xv = *reinterpret_cast<const float4*>(&xs[r][k]);
            acc[r] = fmaf(xv.x, w0, acc[r]);
            acc[r] = fmaf(xv.y, w1, acc[r]);
            acc[r] = fmaf(xv.z, w2, acc[r]);
            acc[r] = fmaf(xv.w, w3, acc[r]);
        }
    }
#pragma unroll
    for (int r = 0; r < 16; ++r) {
        int rr = r0 + r;
        if (rr < NN) H[rr * D + d] = acc[r];
    }
}

// ---- aggregate: wave per node, float2 per lane, register broadcast ------
// out[c] = relu( dinv[c]*( sum_e dinv[src]*w*H[src] + dinv[c]*H[c] ) + b )

__global__ __launch_bounds__(256) void agg_kernel(const float* __restrict__ H,
                                                  const int* __restrict__ cnt,
                                                  const int2* __restrict__ epack,
                                                  const float* __restrict__ dinv,
                                                  const float* __restrict__ bias,
                                                  float* __restrict__ out) {
    int node = blockIdx.x * 4 + (threadIdx.x >> 6);
    if (node >= NN) return;
    int lane = threadIdx.x & 63;
    int d2   = lane * 2;
    int m    = cnt[node];
    const int2* ebase = epack + ((size_t)node << PAD_SHIFT);
    float di = dinv[node];
    float2 hc = *reinterpret_cast<const float2*>(&H[node * D + d2]);
    float accx = di * hc.x;                  // self-loop (x di in epilogue)
    float accy = di * hc.y;

    int jb = 0;
    for (; jb + 64 <= m; jb += 64) {         // full chunks: compile-time shfl lanes
        int2 v = ebase[jb + lane];
        int   src = v.x;
        float n   = dinv[src] * __int_as_float(v.y);
#pragma unroll
        for (int jj = 0; jj < 64; ++jj) {
            int   s_j = __shfl(src, jj);
            float n_j = __shfl(n, jj);
            float2 hv = *reinterpret_cast<const float2*>(&H[s_j * D + d2]);
            accx = fmaf(n_j, hv.x, accx);
            accy = fmaf(n_j, hv.y, accy);
        }
    }
    {                                        // tail
        int rem = m - jb;
        int   src = 0;
        float n   = 0.0f;
        if (lane < rem) {
            int2 v = ebase[jb + lane];
            src = v.x;
            n   = dinv[src] * __int_as_float(v.y);
        }
        for (int jj = 0; jj < rem; ++jj) {
            int   s_j = __shfl(src, jj);
            float n_j = __shfl(n, jj);
            float2 hv = *reinterpret_cast<const float2*>(&H[s_j * D + d2]);
            accx = fmaf(n_j, hv.x, accx);
            accy = fmaf(n_j, hv.y, accy);
        }
    }
    float bx = bias[d2], by = bias[d2 + 1];
    out[node * D + d2]     = fmaxf(fmaf(di, accx, bx), 0.0f);
    out[node * D + d2 + 1] = fmaxf(fmaf(di, accy, by), 0.0f);
}

// ---- launch -------------------------------------------------------------

extern "C" void kernel_launch(void* const* d_in, const int* in_sizes, int n_in,
                              void* d_out, int out_size, void* d_ws, size_t ws_size,
                              hipStream_t stream) {
    const float* x  = (const float*)d_in[0];
    const int*   ei = (const int*)  d_in[1];   // [2, NE]
    const float* ew = (const float*)d_in[2];
    const float* W1 = (const float*)d_in[3];
    const float* b1 = (const float*)d_in[4];
    const float* W2 = (const float*)d_in[5];
    const float* b2 = (const float*)d_in[6];
    float* out = (float*)d_out;

    char* ws = (char*)d_ws;
    size_t off = 0;
    auto alloc = [&](size_t bytes) {
        void* p = ws + off;
        off = (off + bytes + 255) & ~(size_t)255;
        return p;
    };
    int*   cnt   = (int*)  alloc(NN * 4);
    float* dinv  = (float*)alloc(NN * 4);
    int2*  epack = (int2*) alloc(((size_t)NN << PAD_SHIFT) * 8);
    float* h     = (float*)alloc((size_t)NN * D * 4);
    float* g     = (float*)alloc((size_t)NN * D * 4);

    zero_kernel         <<<(NN + 255) / 256, 256, 0, stream>>>(cnt, NN);
    count_scatter_kernel<<<(NE + 255) / 256, 256, 0, stream>>>(ei, ew, cnt, epack);
    degdinv_kernel      <<<(NN + 3) / 4, 256, 0, stream>>>(cnt, epack, dinv);

    gemm_kernel<<<NN / 16, 128, 0, stream>>>(x, W1, h);
    agg_kernel <<<(NN + 3) / 4, 256, 0, stream>>>(h, cnt, epack, dinv, b1, g);
    gemm_kernel<<<NN / 16, 128, 0, stream>>>(g, W2, h);
    agg_kernel <<<(NN + 3) / 4, 256, 0, stream>>>(h, cnt, epack, dinv, b2, out);
}

// Round 5
// 171.623 us; speedup vs baseline: 1.2484x; 1.2484x over previous
//
#include <hip/hip_runtime.h>

#define NN 10000
#define NE 640000
#define D  128
#define PAD_SHIFT 7              // 128 slots/node; P(deg>=128 | mean 64) ~ 3e-12/node

// ---- zero the per-node counters ----------------------------------------

__global__ __launch_bounds__(256) void zero_kernel(int* __restrict__ p, int n) {
    int i = blockIdx.x * 256 + threadIdx.x;
    if (i < n) p[i] = 0;
}

// ---- pass 1: rank only (atomic result goes to a streaming store) --------

__global__ __launch_bounds__(256) void count_rank_kernel(const int* __restrict__ ei,
                                                         int* __restrict__ cnt,
                                                         int* __restrict__ rank) {
    int e = blockIdx.x * 256 + threadIdx.x;
    if (e < NE) {
        int c = ei[NE + e];
        rank[e] = atomicAdd(&cnt[c], 1);
    }
}

// ---- pass 2: atomic-free scatter into padded CSR ------------------------

__global__ __launch_bounds__(256) void scatter_kernel(const int* __restrict__ ei,
                                                      const float* __restrict__ ew,
                                                      const int* __restrict__ rank,
                                                      int2* __restrict__ epack) {
    int e = blockIdx.x * 256 + threadIdx.x;
    if (e < NE) {
        int r = ei[e];
        int c = ei[NE + e];
        int2 v;
        v.x = r;
        v.y = __float_as_int(ew[e]);
        epack[((size_t)c << PAD_SHIFT) + rank[e]] = v;
    }
}

// ---- deg -> dinv from padded CSR, wave per node -------------------------

__global__ __launch_bounds__(256) void degdinv_kernel(const int* __restrict__ cnt,
                                                      const int2* __restrict__ epack,
                                                      float* __restrict__ dinv) {
    int node = blockIdx.x * 4 + (threadIdx.x >> 6);
    if (node >= NN) return;
    int lane = threadIdx.x & 63;
    int m = cnt[node];
    const int2* base = epack + ((size_t)node << PAD_SHIFT);
    float s = 0.0f;
    for (int j = lane; j < m; j += 64) s += __int_as_float(base[j].y);
#pragma unroll
    for (int off = 32; off; off >>= 1) s += __shfl_down(s, off);
    if (lane == 0) dinv[node] = rsqrtf(s + 1.0f);      // +1 = self loop
}

// ---- dense H = X @ W ----------------------------------------------------

__global__ __launch_bounds__(128) void gemm_kernel(const float* __restrict__ X,
                                                   const float* __restrict__ W,
                                                   float* __restrict__ H) {
    __shared__ float xs[16][D];
    int r0 = blockIdx.x * 16;
    int d  = threadIdx.x;
#pragma unroll
    for (int r = 0; r < 16; ++r) {
        int rr = r0 + r;
        xs[r][d] = (rr < NN) ? X[rr * D + d] : 0.0f;
    }
    __syncthreads();
    float acc[16];
#pragma unroll
    for (int r = 0; r < 16; ++r) acc[r] = 0.0f;
    for (int k = 0; k < D; k += 4) {
        float w0 = W[(k + 0) * D + d];
        float w1 = W[(k + 1) * D + d];
        float w2 = W[(k + 2) * D + d];
        float w3 = W[(k + 3) * D + d];
#pragma unroll
        for (int r = 0; r < 16; ++r) {
            float4 xv = *reinterpret_cast<const float4*>(&xs[r][k]);
            acc[r] = fmaf(xv.x, w0, acc[r]);
            acc[r] = fmaf(xv.y, w1, acc[r]);
            acc[r] = fmaf(xv.z, w2, acc[r]);
            acc[r] = fmaf(xv.w, w3, acc[r]);
        }
    }
#pragma unroll
    for (int r = 0; r < 16; ++r) {
        int rr = r0 + r;
        if (rr < NN) H[rr * D + d] = acc[r];
    }
}

// ---- aggregate: wave/node, 2 edges per iter, float4/lane ----------------
// half-wave h = lane>>5 handles edge 2p+h; 32 lanes x float4 = one 512B row.
// out[c] = relu( dinv[c]*( sum_e dinv[src]*w*H[src] + dinv[c]*H[c] ) + b )

__global__ __launch_bounds__(256, 4) void agg_kernel(const float* __restrict__ H,
                                                     const int* __restrict__ cnt,
                                                     const int2* __restrict__ epack,
                                                     const float* __restrict__ dinv,
                                                     const float* __restrict__ bias,
                                                     float* __restrict__ out) {
    int node = blockIdx.x * 4 + (threadIdx.x >> 6);
    if (node >= NN) return;
    int lane = threadIdx.x & 63;
    int h = lane >> 5;            // which edge of the pair
    int q = lane & 31;            // 16B chunk within the row
    int m = cnt[node];
    const int2* ebase = epack + ((size_t)node << PAD_SHIFT);
    float di = dinv[node];

    float4 acc = {0.f, 0.f, 0.f, 0.f};
    if (h == 0) {                 // self-loop term (x di in epilogue)
        float4 hc = *reinterpret_cast<const float4*>(&H[(size_t)node * D + q * 4]);
        acc.x = di * hc.x; acc.y = di * hc.y; acc.z = di * hc.z; acc.w = di * hc.w;
    }

    for (int jb = 0; jb < m; jb += 64) {
        int rem = m - jb;                       // may exceed 64
        int bcnt = rem < 64 ? rem : 64;
        int   src = node;
        float n   = 0.0f;
        if (lane < bcnt) {
            int2 v = ebase[jb + lane];
            src = v.x;
            n   = dinv[src] * __int_as_float(v.y);
        }
        if (bcnt == 64) {
#pragma unroll
            for (int p = 0; p < 32; ++p) {
                int   s_ = __shfl(src, 2 * p + h);
                float n_ = __shfl(n,   2 * p + h);
                float4 hv = *reinterpret_cast<const float4*>(&H[(size_t)s_ * D + q * 4]);
                acc.x = fmaf(n_, hv.x, acc.x);
                acc.y = fmaf(n_, hv.y, acc.y);
                acc.z = fmaf(n_, hv.z, acc.z);
                acc.w = fmaf(n_, hv.w, acc.w);
            }
        } else {
            int pairs = bcnt >> 1;
            for (int p = 0; p < pairs; ++p) {
                int   s_ = __shfl(src, 2 * p + h);
                float n_ = __shfl(n,   2 * p + h);
                float4 hv = *reinterpret_cast<const float4*>(&H[(size_t)s_ * D + q * 4]);
                acc.x = fmaf(n_, hv.x, acc.x);
                acc.y = fmaf(n_, hv.y, acc.y);
                acc.z = fmaf(n_, hv.z, acc.z);
                acc.w = fmaf(n_, hv.w, acc.w);
            }
            if (bcnt & 1) {                     // last odd edge: half 0 only
                int   s_ = __shfl(src, bcnt - 1);
                float n_ = __shfl(n,   bcnt - 1);
                if (h == 0) {
                    float4 hv = *reinterpret_cast<const float4*>(&H[(size_t)s_ * D + q * 4]);
                    acc.x = fmaf(n_, hv.x, acc.x);
                    acc.y = fmaf(n_, hv.y, acc.y);
                    acc.z = fmaf(n_, hv.z, acc.z);
                    acc.w = fmaf(n_, hv.w, acc.w);
                }
            }
        }
    }

    // combine the two halves
    acc.x += __shfl_xor(acc.x, 32);
    acc.y += __shfl_xor(acc.y, 32);
    acc.z += __shfl_xor(acc.z, 32);
    acc.w += __shfl_xor(acc.w, 32);

    if (h == 0) {
        float4 b4 = *reinterpret_cast<const float4*>(&bias[q * 4]);
        float4 o;
        o.x = fmaxf(fmaf(di, acc.x, b4.x), 0.f);
        o.y = fmaxf(fmaf(di, acc.y, b4.y), 0.f);
        o.z = fmaxf(fmaf(di, acc.z, b4.z), 0.f);
        o.w = fmaxf(fmaf(di, acc.w, b4.w), 0.f);
        *reinterpret_cast<float4*>(&out[(size_t)node * D + q * 4]) = o;
    }
}

// ---- launch -------------------------------------------------------------

extern "C" void kernel_launch(void* const* d_in, const int* in_sizes, int n_in,
                              void* d_out, int out_size, void* d_ws, size_t ws_size,
                              hipStream_t stream) {
    const float* x  = (const float*)d_in[0];
    const int*   ei = (const int*)  d_in[1];   // [2, NE]
    const float* ew = (const float*)d_in[2];
    const float* W1 = (const float*)d_in[3];
    const float* b1 = (const float*)d_in[4];
    const float* W2 = (const float*)d_in[5];
    const float* b2 = (const float*)d_in[6];
    float* out = (float*)d_out;

    char* ws = (char*)d_ws;
    size_t off = 0;
    auto alloc = [&](size_t bytes) {
        void* p = ws + off;
        off = (off + bytes + 255) & ~(size_t)255;
        return p;
    };
    int*   cnt   = (int*)  alloc(NN * 4);
    float* dinv  = (float*)alloc(NN * 4);
    int*   rank  = (int*)  alloc((size_t)NE * 4);
    int2*  epack = (int2*) alloc(((size_t)NN << PAD_SHIFT) * 8);
    float* h     = (float*)alloc((size_t)NN * D * 4);
    float* g     = (float*)alloc((size_t)NN * D * 4);

    zero_kernel      <<<(NN + 255) / 256, 256, 0, stream>>>(cnt, NN);
    count_rank_kernel<<<(NE + 255) / 256, 256, 0, stream>>>(ei, cnt, rank);
    scatter_kernel   <<<(NE + 255) / 256, 256, 0, stream>>>(ei, ew, rank, epack);
    degdinv_kernel   <<<(NN + 3) / 4, 256, 0, stream>>>(cnt, epack, dinv);

    gemm_kernel<<<NN / 16, 128, 0, stream>>>(x, W1, h);
    agg_kernel <<<(NN + 3) / 4, 256, 0, stream>>>(h, cnt, epack, dinv, b1, g);
    gemm_kernel<<<NN / 16, 128, 0, stream>>>(g, W2, h);
    agg_kernel <<<(NN + 3) / 4, 256, 0, stream>>>(h, cnt, epack, dinv, b2, out);
}

// Round 6
// 158.202 us; speedup vs baseline: 1.3543x; 1.0848x over previous
//
#include <hip/hip_runtime.h>

#define NN 10000
#define NE 640000
#define D  128
#define PAD_SHIFT 7              // 128 slots/node; P(deg>=128 | mean 64) ~ 3e-13/node
#define GEMM_BLOCKS ((NN + 31) / 32)

// ---- zero the per-node counters ----------------------------------------

__global__ __launch_bounds__(256) void zero_kernel(int* __restrict__ p, int n) {
    int i = blockIdx.x * 256 + threadIdx.x;
    if (i < n) p[i] = 0;
}

// ---- fused: gemm1 (blocks [0,GEMM_BLOCKS)) + count_rank (rest) ----------
// independent work overlapped in one dispatch: count_rank is atomic-latency
// bound and leaves VALU+BW idle; gemm rides underneath.

__global__ __launch_bounds__(256) void fused_gemm_count_kernel(const float* __restrict__ X,
                                                               const float* __restrict__ W,
                                                               float* __restrict__ H,
                                                               const int* __restrict__ ei,
                                                               int* __restrict__ cnt,
                                                               int* __restrict__ rank) {
    int bid = blockIdx.x;
    if (bid < GEMM_BLOCKS) {
        // ---- gemm: 32 rows/block, 256 threads: d = t&127, row-half = t>>7
        __shared__ float xs[32][D];
        int t  = threadIdx.x;
        int d  = t & 127;
        int rh = t >> 7;                 // 0 or 1 -> rows rh*16..rh*16+15
        int r0 = bid * 32;
#pragma unroll
        for (int r = 0; r < 16; ++r) {
            int rr = r0 + rh * 16 + r;
            xs[rh * 16 + r][d] = (rr < NN) ? X[(size_t)rr * D + d] : 0.0f;
        }
        __syncthreads();
        float acc[16];
#pragma unroll
        for (int r = 0; r < 16; ++r) acc[r] = 0.0f;
        for (int k = 0; k < D; k += 4) {
            float w0 = W[(k + 0) * D + d];
            float w1 = W[(k + 1) * D + d];
            float w2 = W[(k + 2) * D + d];
            float w3 = W[(k + 3) * D + d];
#pragma unroll
            for (int r = 0; r < 16; ++r) {
                float4 xv = *reinterpret_cast<const float4*>(&xs[rh * 16 + r][k]);
                acc[r] = fmaf(xv.x, w0, acc[r]);
                acc[r] = fmaf(xv.y, w1, acc[r]);
                acc[r] = fmaf(xv.z, w2, acc[r]);
                acc[r] = fmaf(xv.w, w3, acc[r]);
            }
        }
#pragma unroll
        for (int r = 0; r < 16; ++r) {
            int rr = r0 + rh * 16 + r;
            if (rr < NN) H[(size_t)rr * D + d] = acc[r];
        }
    } else {
        int e = (bid - GEMM_BLOCKS) * 256 + threadIdx.x;
        if (e < NE) {
            int c = ei[NE + e];
            rank[e] = atomicAdd(&cnt[c], 1);
        }
    }
}

// ---- atomic-free scatter into padded CSR --------------------------------

__global__ __launch_bounds__(256) void scatter_kernel(const int* __restrict__ ei,
                                                      const float* __restrict__ ew,
                                                      const int* __restrict__ rank,
                                                      int2* __restrict__ epack) {
    int e = blockIdx.x * 256 + threadIdx.x;
    if (e < NE) {
        int2 v;
        v.x = ei[e];                     // source
        v.y = __float_as_int(ew[e]);
        int c = ei[NE + e];
        epack[((size_t)c << PAD_SHIFT) + rank[e]] = v;
    }
}

// ---- deg -> dinv from padded CSR, wave per node -------------------------

__global__ __launch_bounds__(256) void degdinv_kernel(const int* __restrict__ cnt,
                                                      const int2* __restrict__ epack,
                                                      float* __restrict__ dinv) {
    int node = blockIdx.x * 4 + (threadIdx.x >> 6);
    if (node >= NN) return;
    int lane = threadIdx.x & 63;
    int m = cnt[node];
    const int2* base = epack + ((size_t)node << PAD_SHIFT);
    float s = 0.0f;
    for (int j = lane; j < m; j += 64) s += __int_as_float(base[j].y);
#pragma unroll
    for (int off = 32; off; off >>= 1) s += __shfl_down(s, off);
    if (lane == 0) dinv[node] = rsqrtf(s + 1.0f);      // +1 = self loop
}

// ---- plain gemm (layer 2): 32 rows/block, 256 threads -------------------

__global__ __launch_bounds__(256) void gemm_kernel(const float* __restrict__ X,
                                                   const float* __restrict__ W,
                                                   float* __restrict__ H) {
    __shared__ float xs[32][D];
    int t  = threadIdx.x;
    int d  = t & 127;
    int rh = t >> 7;
    int r0 = blockIdx.x * 32;
#pragma unroll
    for (int r = 0; r < 16; ++r) {
        int rr = r0 + rh * 16 + r;
        xs[rh * 16 + r][d] = (rr < NN) ? X[(size_t)rr * D + d] : 0.0f;
    }
    __syncthreads();
    float acc[16];
#pragma unroll
    for (int r = 0; r < 16; ++r) acc[r] = 0.0f;
    for (int k = 0; k < D; k += 4) {
        float w0 = W[(k + 0) * D + d];
        float w1 = W[(k + 1) * D + d];
        float w2 = W[(k + 2) * D + d];
        float w3 = W[(k + 3) * D + d];
#pragma unroll
        for (int r = 0; r < 16; ++r) {
            float4 xv = *reinterpret_cast<const float4*>(&xs[rh * 16 + r][k]);
            acc[r] = fmaf(xv.x, w0, acc[r]);
            acc[r] = fmaf(xv.y, w1, acc[r]);
            acc[r] = fmaf(xv.z, w2, acc[r]);
            acc[r] = fmaf(xv.w, w3, acc[r]);
        }
    }
#pragma unroll
    for (int r = 0; r < 16; ++r) {
        int rr = r0 + rh * 16 + r;
        if (rr < NN) H[(size_t)rr * D + d] = acc[r];
    }
}

// ---- aggregate: 32-lane group per node, 8 nodes/block, unroll-8 ---------
// lane q owns float4 chunk q of the row; edge meta via group-uniform loads
// (L1 broadcast); 8 independent H-gathers in flight per lane.
// out[c] = relu( dinv[c]*( sum_e dinv[src]*w*H[src] + dinv[c]*H[c] ) + b )

__global__ __launch_bounds__(256) void agg_kernel(const float* __restrict__ H,
                                                  const int* __restrict__ cnt,
                                                  const int2* __restrict__ epack,
                                                  const float* __restrict__ dinv,
                                                  const float* __restrict__ bias,
                                                  float* __restrict__ out) {
    int node = blockIdx.x * 8 + (threadIdx.x >> 5);
    if (node >= NN) return;
    int q = threadIdx.x & 31;
    int m = cnt[node];
    const int2* eb = epack + ((size_t)node << PAD_SHIFT);
    const float4* Hq = reinterpret_cast<const float4*>(H) + q;   // row r -> Hq[r*32]
    float di = dinv[node];

    float4 hc = Hq[(size_t)node * 32];
    float4 acc;
    acc.x = di * hc.x; acc.y = di * hc.y; acc.z = di * hc.z; acc.w = di * hc.w;

    int j = 0;
    for (; j + 8 <= m; j += 8) {
        int   s[8];
        float n[8];
#pragma unroll
        for (int k = 0; k < 8; ++k) {
            int2 v = eb[j + k];
            s[k] = v.x;
            n[k] = dinv[v.x] * __int_as_float(v.y);
        }
#pragma unroll
        for (int k = 0; k < 8; ++k) {
            float4 hv = Hq[(size_t)s[k] * 32];
            acc.x = fmaf(n[k], hv.x, acc.x);
            acc.y = fmaf(n[k], hv.y, acc.y);
            acc.z = fmaf(n[k], hv.z, acc.z);
            acc.w = fmaf(n[k], hv.w, acc.w);
        }
    }
    for (; j < m; ++j) {
        int2 v = eb[j];
        float nn = dinv[v.x] * __int_as_float(v.y);
        float4 hv = Hq[(size_t)v.x * 32];
        acc.x = fmaf(nn, hv.x, acc.x);
        acc.y = fmaf(nn, hv.y, acc.y);
        acc.z = fmaf(nn, hv.z, acc.z);
        acc.w = fmaf(nn, hv.w, acc.w);
    }

    float4 b4 = reinterpret_cast<const float4*>(bias)[q];
    float4 o;
    o.x = fmaxf(fmaf(di, acc.x, b4.x), 0.f);
    o.y = fmaxf(fmaf(di, acc.y, b4.y), 0.f);
    o.z = fmaxf(fmaf(di, acc.z, b4.z), 0.f);
    o.w = fmaxf(fmaf(di, acc.w, b4.w), 0.f);
    reinterpret_cast<float4*>(out)[(size_t)node * 32 + q] = o;
}

// ---- launch -------------------------------------------------------------

extern "C" void kernel_launch(void* const* d_in, const int* in_sizes, int n_in,
                              void* d_out, int out_size, void* d_ws, size_t ws_size,
                              hipStream_t stream) {
    const float* x  = (const float*)d_in[0];
    const int*   ei = (const int*)  d_in[1];   // [2, NE]
    const float* ew = (const float*)d_in[2];
    const float* W1 = (const float*)d_in[3];
    const float* b1 = (const float*)d_in[4];
    const float* W2 = (const float*)d_in[5];
    const float* b2 = (const float*)d_in[6];
    float* out = (float*)d_out;

    char* ws = (char*)d_ws;
    size_t off = 0;
    auto alloc = [&](size_t bytes) {
        void* p = ws + off;
        off = (off + bytes + 255) & ~(size_t)255;
        return p;
    };
    int*   cnt   = (int*)  alloc(NN * 4);
    float* dinv  = (float*)alloc(NN * 4);
    int*   rank  = (int*)  alloc((size_t)NE * 4);
    int2*  epack = (int2*) alloc(((size_t)NN << PAD_SHIFT) * 8);
    float* h     = (float*)alloc((size_t)NN * D * 4);
    float* g     = (float*)alloc((size_t)NN * D * 4);

    zero_kernel<<<(NN + 255) / 256, 256, 0, stream>>>(cnt, NN);
    fused_gemm_count_kernel<<<GEMM_BLOCKS + (NE + 255) / 256, 256, 0, stream>>>(
        x, W1, h, ei, cnt, rank);
    scatter_kernel<<<(NE + 255) / 256, 256, 0, stream>>>(ei, ew, rank, epack);
    degdinv_kernel<<<(NN + 3) / 4, 256, 0, stream>>>(cnt, epack, dinv);

    agg_kernel <<<(NN + 7) / 8, 256, 0, stream>>>(h, cnt, epack, dinv, b1, g);
    gemm_kernel<<<(NN + 31) / 32, 256, 0, stream>>>(g, W2, h);
    agg_kernel <<<(NN + 7) / 8, 256, 0, stream>>>(h, cnt, epack, dinv, b2, out);
}

// Round 7
// 146.263 us; speedup vs baseline: 1.4648x; 1.0816x over previous
//
#include <hip/hip_runtime.h>

#define NN 10000
#define NE 640000
#define D  128
#define PAD_SHIFT 7              // 128 slots/node; P(deg>=128 | mean 64) ~ 3e-13/node
#define GEMM_BLOCKS ((NN + 31) / 32)
#define CSTRIDE 10240            // per-XCD counter replica stride (line-aligned regions)

// physical XCD id of the wave (0..7 on MI355X). Uniform within a workgroup.
__device__ __forceinline__ int xcc_id() {
    unsigned x;
    asm volatile("s_getreg_b32 %0, hwreg(HW_REG_XCC_ID)" : "=s"(x));
    return (int)(x & 7);
}

// ---- zero the per-XCD counter replicas ----------------------------------

__global__ __launch_bounds__(256) void zero_kernel(int* __restrict__ p, int n) {
    int i = blockIdx.x * 256 + threadIdx.x;
    if (i < n) p[i] = 0;
}

// ---- fused: gemm1 (blocks [0,GEMM_BLOCKS)) + count_rank (rest) ----------
// count uses XCD-LOCAL (workgroup-scope) atomics: the RMW stays in the local
// XCD L2 instead of write-through coherence traffic to HBM.

__global__ __launch_bounds__(256) void fused_gemm_count_kernel(const float* __restrict__ X,
                                                               const float* __restrict__ W,
                                                               float* __restrict__ H,
                                                               const int* __restrict__ ei,
                                                               int* __restrict__ cnt8,
                                                               int* __restrict__ rank) {
    int bid = blockIdx.x;
    if (bid < GEMM_BLOCKS) {
        __shared__ float xs[32][D];
        int t  = threadIdx.x;
        int d  = t & 127;
        int rh = t >> 7;
        int r0 = bid * 32;
#pragma unroll
        for (int r = 0; r < 16; ++r) {
            int rr = r0 + rh * 16 + r;
            xs[rh * 16 + r][d] = (rr < NN) ? X[(size_t)rr * D + d] : 0.0f;
        }
        __syncthreads();
        float acc[16];
#pragma unroll
        for (int r = 0; r < 16; ++r) acc[r] = 0.0f;
        for (int k = 0; k < D; k += 4) {
            float w0 = W[(k + 0) * D + d];
            float w1 = W[(k + 1) * D + d];
            float w2 = W[(k + 2) * D + d];
            float w3 = W[(k + 3) * D + d];
#pragma unroll
            for (int r = 0; r < 16; ++r) {
                float4 xv = *reinterpret_cast<const float4*>(&xs[rh * 16 + r][k]);
                acc[r] = fmaf(xv.x, w0, acc[r]);
                acc[r] = fmaf(xv.y, w1, acc[r]);
                acc[r] = fmaf(xv.z, w2, acc[r]);
                acc[r] = fmaf(xv.w, w3, acc[r]);
            }
        }
#pragma unroll
        for (int r = 0; r < 16; ++r) {
            int rr = r0 + rh * 16 + r;
            if (rr < NN) H[(size_t)rr * D + d] = acc[r];
        }
    } else {
        int e = (bid - GEMM_BLOCKS) * 256 + threadIdx.x;
        if (e < NE) {
            int c = ei[NE + e];
            int x = xcc_id();
            int lr = __hip_atomic_fetch_add(&cnt8[x * CSTRIDE + c], 1,
                                            __ATOMIC_RELAXED,
                                            __HIP_MEMORY_SCOPE_WORKGROUP);
            rank[e] = (x << 16) | lr;
        }
    }
}

// ---- per-node 8-way prefix: cnt8 -> base8 (in place) + total cnt --------
// padded CSR means bases are node-local: no global scan.

__global__ __launch_bounds__(256) void base_kernel(int* __restrict__ cnt8,
                                                   int* __restrict__ cnt) {
    int n = blockIdx.x * 256 + threadIdx.x;
    if (n >= NN) return;
    int b = 0;
#pragma unroll
    for (int x = 0; x < 8; ++x) {
        int t = cnt8[x * CSTRIDE + n];
        cnt8[x * CSTRIDE + n] = b;     // exclusive prefix = this XCD's base
        b += t;
    }
    cnt[n] = b;
}

// ---- atomic-free scatter into padded CSR --------------------------------

__global__ __launch_bounds__(256) void scatter_kernel(const int* __restrict__ ei,
                                                      const float* __restrict__ ew,
                                                      const int* __restrict__ rank,
                                                      const int* __restrict__ base8,
                                                      int2* __restrict__ epack) {
    int e = blockIdx.x * 256 + threadIdx.x;
    if (e < NE) {
        int c  = ei[NE + e];
        int rk = rank[e];
        int x  = rk >> 16;
        int lr = rk & 0xFFFF;
        int2 v;
        v.x = ei[e];
        v.y = __float_as_int(ew[e]);
        epack[((size_t)c << PAD_SHIFT) + base8[x * CSTRIDE + c] + lr] = v;
    }
}

// ---- deg -> dinv from padded CSR, wave per node -------------------------

__global__ __launch_bounds__(256) void degdinv_kernel(const int* __restrict__ cnt,
                                                      const int2* __restrict__ epack,
                                                      float* __restrict__ dinv) {
    int node = blockIdx.x * 4 + (threadIdx.x >> 6);
    if (node >= NN) return;
    int lane = threadIdx.x & 63;
    int m = cnt[node];
    const int2* base = epack + ((size_t)node << PAD_SHIFT);
    float s = 0.0f;
    for (int j = lane; j < m; j += 64) s += __int_as_float(base[j].y);
#pragma unroll
    for (int off = 32; off; off >>= 1) s += __shfl_down(s, off);
    if (lane == 0) dinv[node] = rsqrtf(s + 1.0f);      // +1 = self loop
}

// ---- plain gemm (layer 2): 32 rows/block, 256 threads -------------------

__global__ __launch_bounds__(256) void gemm_kernel(const float* __restrict__ X,
                                                   const float* __restrict__ W,
                                                   float* __restrict__ H) {
    __shared__ float xs[32][D];
    int t  = threadIdx.x;
    int d  = t & 127;
    int rh = t >> 7;
    int r0 = blockIdx.x * 32;
#pragma unroll
    for (int r = 0; r < 16; ++r) {
        int rr = r0 + rh * 16 + r;
        xs[rh * 16 + r][d] = (rr < NN) ? X[(size_t)rr * D + d] : 0.0f;
    }
    __syncthreads();
    float acc[16];
#pragma unroll
    for (int r = 0; r < 16; ++r) acc[r] = 0.0f;
    for (int k = 0; k < D; k += 4) {
        float w0 = W[(k + 0) * D + d];
        float w1 = W[(k + 1) * D + d];
        float w2 = W[(k + 2) * D + d];
        float w3 = W[(k + 3) * D + d];
#pragma unroll
        for (int r = 0; r < 16; ++r) {
            float4 xv = *reinterpret_cast<const float4*>(&xs[rh * 16 + r][k]);
            acc[r] = fmaf(xv.x, w0, acc[r]);
            acc[r] = fmaf(xv.y, w1, acc[r]);
            acc[r] = fmaf(xv.z, w2, acc[r]);
            acc[r] = fmaf(xv.w, w3, acc[r]);
        }
    }
#pragma unroll
    for (int r = 0; r < 16; ++r) {
        int rr = r0 + rh * 16 + r;
        if (rr < NN) H[(size_t)rr * D + d] = acc[r];
    }
}

// ---- aggregate: 32-lane group per node, 8 nodes/block, unroll-8 ---------

__global__ __launch_bounds__(256) void agg_kernel(const float* __restrict__ H,
                                                  const int* __restrict__ cnt,
                                                  const int2* __restrict__ epack,
                                                  const float* __restrict__ dinv,
                                                  const float* __restrict__ bias,
                                                  float* __restrict__ out) {
    int node = blockIdx.x * 8 + (threadIdx.x >> 5);
    if (node >= NN) return;
    int q = threadIdx.x & 31;
    int m = cnt[node];
    const int2* eb = epack + ((size_t)node << PAD_SHIFT);
    const float4* Hq = reinterpret_cast<const float4*>(H) + q;   // row r -> Hq[r*32]
    float di = dinv[node];

    float4 hc = Hq[(size_t)node * 32];
    float4 acc;
    acc.x = di * hc.x; acc.y = di * hc.y; acc.z = di * hc.z; acc.w = di * hc.w;

    int j = 0;
    for (; j + 8 <= m; j += 8) {
        int   s[8];
        float n[8];
#pragma unroll
        for (int k = 0; k < 8; ++k) {
            int2 v = eb[j + k];
            s[k] = v.x;
            n[k] = dinv[v.x] * __int_as_float(v.y);
        }
#pragma unroll
        for (int k = 0; k < 8; ++k) {
            float4 hv = Hq[(size_t)s[k] * 32];
            acc.x = fmaf(n[k], hv.x, acc.x);
            acc.y = fmaf(n[k], hv.y, acc.y);
            acc.z = fmaf(n[k], hv.z, acc.z);
            acc.w = fmaf(n[k], hv.w, acc.w);
        }
    }
    for (; j < m; ++j) {
        int2 v = eb[j];
        float nn = dinv[v.x] * __int_as_float(v.y);
        float4 hv = Hq[(size_t)v.x * 32];
        acc.x = fmaf(nn, hv.x, acc.x);
        acc.y = fmaf(nn, hv.y, acc.y);
        acc.z = fmaf(nn, hv.z, acc.z);
        acc.w = fmaf(nn, hv.w, acc.w);
    }

    float4 b4 = reinterpret_cast<const float4*>(bias)[q];
    float4 o;
    o.x = fmaxf(fmaf(di, acc.x, b4.x), 0.f);
    o.y = fmaxf(fmaf(di, acc.y, b4.y), 0.f);
    o.z = fmaxf(fmaf(di, acc.z, b4.z), 0.f);
    o.w = fmaxf(fmaf(di, acc.w, b4.w), 0.f);
    reinterpret_cast<float4*>(out)[(size_t)node * 32 + q] = o;
}

// ---- launch -------------------------------------------------------------

extern "C" void kernel_launch(void* const* d_in, const int* in_sizes, int n_in,
                              void* d_out, int out_size, void* d_ws, size_t ws_size,
                              hipStream_t stream) {
    const float* x  = (const float*)d_in[0];
    const int*   ei = (const int*)  d_in[1];   // [2, NE]
    const float* ew = (const float*)d_in[2];
    const float* W1 = (const float*)d_in[3];
    const float* b1 = (const float*)d_in[4];
    const float* W2 = (const float*)d_in[5];
    const float* b2 = (const float*)d_in[6];
    float* out = (float*)d_out;

    char* ws = (char*)d_ws;
    size_t off = 0;
    auto alloc = [&](size_t bytes) {
        void* p = ws + off;
        off = (off + bytes + 255) & ~(size_t)255;
        return p;
    };
    int*   cnt8  = (int*)  alloc(8 * CSTRIDE * 4);
    int*   cnt   = (int*)  alloc(NN * 4);
    float* dinv  = (float*)alloc(NN * 4);
    int*   rank  = (int*)  alloc((size_t)NE * 4);
    int2*  epack = (int2*) alloc(((size_t)NN << PAD_SHIFT) * 8);
    float* h     = (float*)alloc((size_t)NN * D * 4);
    float* g     = (float*)alloc((size_t)NN * D * 4);

    zero_kernel<<<(8 * CSTRIDE + 255) / 256, 256, 0, stream>>>(cnt8, 8 * CSTRIDE);
    fused_gemm_count_kernel<<<GEMM_BLOCKS + (NE + 255) / 256, 256, 0, stream>>>(
        x, W1, h, ei, cnt8, rank);
    base_kernel   <<<(NN + 255) / 256, 256, 0, stream>>>(cnt8, cnt);
    scatter_kernel<<<(NE + 255) / 256, 256, 0, stream>>>(ei, ew, rank, cnt8, epack);
    degdinv_kernel<<<(NN + 3) / 4, 256, 0, stream>>>(cnt, epack, dinv);

    agg_kernel <<<(NN + 7) / 8, 256, 0, stream>>>(h, cnt, epack, dinv, b1, g);
    gemm_kernel<<<(NN + 31) / 32, 256, 0, stream>>>(g, W2, h);
    agg_kernel <<<(NN + 7) / 8, 256, 0, stream>>>(h, cnt, epack, dinv, b2, out);
}

// Round 8
// 146.214 us; speedup vs baseline: 1.4653x; 1.0003x over previous
//
#include <hip/hip_runtime.h>

#define NN 10000
#define NE 640000
#define D  128
#define PAD_SHIFT 7              // 128 slots/node; P(deg>=128 | mean 64) ~ 3e-13/node
#define GEMM_BLOCKS ((NN + 31) / 32)
#define CSTRIDE 10240            // per-XCD counter replica stride

// physical XCD id of the wave (0..7 on MI355X). Uniform within a workgroup.
__device__ __forceinline__ int xcc_id() {
    unsigned x;
    asm volatile("s_getreg_b32 %0, hwreg(HW_REG_XCC_ID)" : "=s"(x));
    return (int)(x & 7);
}

// XCD-L2-local atomic fetch-add: sc0 (return old) WITHOUT sc1 (no device
// coherence) -> RMW executes in the local XCD's L2, no HBM write-through.
// Safe here because each XCD only touches its own counter replica.
__device__ __forceinline__ int l2_atomic_add(int* p, int v) {
    int old;
    asm volatile("global_atomic_add %0, %1, %2, off sc0\n\t"
                 "s_waitcnt vmcnt(0)"
                 : "=&v"(old)
                 : "v"(p), "v"(v)
                 : "memory");
    return old;
}

// ---- zero the per-XCD counter replicas ----------------------------------

__global__ __launch_bounds__(256) void zero_kernel(int* __restrict__ p, int n) {
    int i = blockIdx.x * 256 + threadIdx.x;
    if (i < n) p[i] = 0;
}

// ---- fused: gemm1 (blocks [0,GEMM_BLOCKS)) + count_rank (rest) ----------

__global__ __launch_bounds__(256) void fused_gemm_count_kernel(const float* __restrict__ X,
                                                               const float* __restrict__ W,
                                                               float* __restrict__ H,
                                                               const int* __restrict__ ei,
                                                               int* __restrict__ cnt8,
                                                               int* __restrict__ rank) {
    int bid = blockIdx.x;
    if (bid < GEMM_BLOCKS) {
        __shared__ float xs[32][D];
        int t  = threadIdx.x;
        int d  = t & 127;
        int rh = t >> 7;
        int r0 = bid * 32;
#pragma unroll
        for (int r = 0; r < 16; ++r) {
            int rr = r0 + rh * 16 + r;
            xs[rh * 16 + r][d] = (rr < NN) ? X[(size_t)rr * D + d] : 0.0f;
        }
        __syncthreads();
        float acc[16];
#pragma unroll
        for (int r = 0; r < 16; ++r) acc[r] = 0.0f;
        for (int k = 0; k < D; k += 4) {
            float w0 = W[(k + 0) * D + d];
            float w1 = W[(k + 1) * D + d];
            float w2 = W[(k + 2) * D + d];
            float w3 = W[(k + 3) * D + d];
#pragma unroll
            for (int r = 0; r < 16; ++r) {
                float4 xv = *reinterpret_cast<const float4*>(&xs[rh * 16 + r][k]);
                acc[r] = fmaf(xv.x, w0, acc[r]);
                acc[r] = fmaf(xv.y, w1, acc[r]);
                acc[r] = fmaf(xv.z, w2, acc[r]);
                acc[r] = fmaf(xv.w, w3, acc[r]);
            }
        }
#pragma unroll
        for (int r = 0; r < 16; ++r) {
            int rr = r0 + rh * 16 + r;
            if (rr < NN) H[(size_t)rr * D + d] = acc[r];
        }
    } else {
        int e = (bid - GEMM_BLOCKS) * 256 + threadIdx.x;
        if (e < NE) {
            int c = ei[NE + e];
            int x = xcc_id();
            int lr = l2_atomic_add(&cnt8[x * CSTRIDE + c], 1);
            rank[e] = (x << 16) | lr;
        }
    }
}

// ---- per-node 8-way prefix: cnt8 -> base8 (in place) + total cnt --------

__global__ __launch_bounds__(256) void base_kernel(int* __restrict__ cnt8,
                                                   int* __restrict__ cnt) {
    int n = blockIdx.x * 256 + threadIdx.x;
    if (n >= NN) return;
    int b = 0;
#pragma unroll
    for (int x = 0; x < 8; ++x) {
        int t = cnt8[x * CSTRIDE + n];
        cnt8[x * CSTRIDE + n] = b;     // exclusive prefix = this XCD's base
        b += t;
    }
    cnt[n] = b;
}

// ---- atomic-free scatter into padded CSR --------------------------------

__global__ __launch_bounds__(256) void scatter_kernel(const int* __restrict__ ei,
                                                      const float* __restrict__ ew,
                                                      const int* __restrict__ rank,
                                                      const int* __restrict__ base8,
                                                      int2* __restrict__ epack) {
    int e = blockIdx.x * 256 + threadIdx.x;
    if (e < NE) {
        int c  = ei[NE + e];
        int rk = rank[e];
        int x  = rk >> 16;
        int lr = rk & 0xFFFF;
        int2 v;
        v.x = ei[e];
        v.y = __float_as_int(ew[e]);
        epack[((size_t)c << PAD_SHIFT) + base8[x * CSTRIDE + c] + lr] = v;
    }
}

// ---- deg -> dinv from padded CSR, wave per node -------------------------

__global__ __launch_bounds__(256) void degdinv_kernel(const int* __restrict__ cnt,
                                                      const int2* __restrict__ epack,
                                                      float* __restrict__ dinv) {
    int node = blockIdx.x * 4 + (threadIdx.x >> 6);
    if (node >= NN) return;
    int lane = threadIdx.x & 63;
    int m = cnt[node];
    const int2* base = epack + ((size_t)node << PAD_SHIFT);
    float s = 0.0f;
    for (int j = lane; j < m; j += 64) s += __int_as_float(base[j].y);
#pragma unroll
    for (int off = 32; off; off >>= 1) s += __shfl_down(s, off);
    if (lane == 0) dinv[node] = rsqrtf(s + 1.0f);      // +1 = self loop
}

// ---- plain gemm (layer 2): 32 rows/block, 256 threads -------------------

__global__ __launch_bounds__(256) void gemm_kernel(const float* __restrict__ X,
                                                   const float* __restrict__ W,
                                                   float* __restrict__ H) {
    __shared__ float xs[32][D];
    int t  = threadIdx.x;
    int d  = t & 127;
    int rh = t >> 7;
    int r0 = blockIdx.x * 32;
#pragma unroll
    for (int r = 0; r < 16; ++r) {
        int rr = r0 + rh * 16 + r;
        xs[rh * 16 + r][d] = (rr < NN) ? X[(size_t)rr * D + d] : 0.0f;
    }
    __syncthreads();
    float acc[16];
#pragma unroll
    for (int r = 0; r < 16; ++r) acc[r] = 0.0f;
    for (int k = 0; k < D; k += 4) {
        float w0 = W[(k + 0) * D + d];
        float w1 = W[(k + 1) * D + d];
        float w2 = W[(k + 2) * D + d];
        float w3 = W[(k + 3) * D + d];
#pragma unroll
        for (int r = 0; r < 16; ++r) {
            float4 xv = *reinterpret_cast<const float4*>(&xs[rh * 16 + r][k]);
            acc[r] = fmaf(xv.x, w0, acc[r]);
            acc[r] = fmaf(xv.y, w1, acc[r]);
            acc[r] = fmaf(xv.z, w2, acc[r]);
            acc[r] = fmaf(xv.w, w3, acc[r]);
        }
    }
#pragma unroll
    for (int r = 0; r < 16; ++r) {
        int rr = r0 + rh * 16 + r;
        if (rr < NN) H[(size_t)rr * D + d] = acc[r];
    }
}

// ---- aggregate: 32-lane group per node, 8 nodes/block, unroll-8 ---------

__global__ __launch_bounds__(256) void agg_kernel(const float* __restrict__ H,
                                                  const int* __restrict__ cnt,
                                                  const int2* __restrict__ epack,
                                                  const float* __restrict__ dinv,
                                                  const float* __restrict__ bias,
                                                  float* __restrict__ out) {
    int node = blockIdx.x * 8 + (threadIdx.x >> 5);
    if (node >= NN) return;
    int q = threadIdx.x & 31;
    int m = cnt[node];
    const int2* eb = epack + ((size_t)node << PAD_SHIFT);
    const float4* Hq = reinterpret_cast<const float4*>(H) + q;   // row r -> Hq[r*32]
    float di = dinv[node];

    float4 hc = Hq[(size_t)node * 32];
    float4 acc;
    acc.x = di * hc.x; acc.y = di * hc.y; acc.z = di * hc.z; acc.w = di * hc.w;

    int j = 0;
    for (; j + 8 <= m; j += 8) {
        int   s[8];
        float n[8];
#pragma unroll
        for (int k = 0; k < 8; ++k) {
            int2 v = eb[j + k];
            s[k] = v.x;
            n[k] = dinv[v.x] * __int_as_float(v.y);
        }
#pragma unroll
        for (int k = 0; k < 8; ++k) {
            float4 hv = Hq[(size_t)s[k] * 32];
            acc.x = fmaf(n[k], hv.x, acc.x);
            acc.y = fmaf(n[k], hv.y, acc.y);
            acc.z = fmaf(n[k], hv.z, acc.z);
            acc.w = fmaf(n[k], hv.w, acc.w);
        }
    }
    for (; j < m; ++j) {
        int2 v = eb[j];
        float nn = dinv[v.x] * __int_as_float(v.y);
        float4 hv = Hq[(size_t)v.x * 32];
        acc.x = fmaf(nn, hv.x, acc.x);
        acc.y = fmaf(nn, hv.y, acc.y);
        acc.z = fmaf(nn, hv.z, acc.z);
        acc.w = fmaf(nn, hv.w, acc.w);
    }

    float4 b4 = reinterpret_cast<const float4*>(bias)[q];
    float4 o;
    o.x = fmaxf(fmaf(di, acc.x, b4.x), 0.f);
    o.y = fmaxf(fmaf(di, acc.y, b4.y), 0.f);
    o.z = fmaxf(fmaf(di, acc.z, b4.z), 0.f);
    o.w = fmaxf(fmaf(di, acc.w, b4.w), 0.f);
    reinterpret_cast<float4*>(out)[(size_t)node * 32 + q] = o;
}

// ---- launch -------------------------------------------------------------

extern "C" void kernel_launch(void* const* d_in, const int* in_sizes, int n_in,
                              void* d_out, int out_size, void* d_ws, size_t ws_size,
                              hipStream_t stream) {
    const float* x  = (const float*)d_in[0];
    const int*   ei = (const int*)  d_in[1];   // [2, NE]
    const float* ew = (const float*)d_in[2];
    const float* W1 = (const float*)d_in[3];
    const float* b1 = (const float*)d_in[4];
    const float* W2 = (const float*)d_in[5];
    const float* b2 = (const float*)d_in[6];
    float* out = (float*)d_out;

    char* ws = (char*)d_ws;
    size_t off = 0;
    auto alloc = [&](size_t bytes) {
        void* p = ws + off;
        off = (off + bytes + 255) & ~(size_t)255;
        return p;
    };
    int*   cnt8  = (int*)  alloc(8 * CSTRIDE * 4);
    int*   cnt   = (int*)  alloc(NN * 4);
    float* dinv  = (float*)alloc(NN * 4);
    int*   rank  = (int*)  alloc((size_t)NE * 4);
    int2*  epack = (int2*) alloc(((size_t)NN << PAD_SHIFT) * 8);
    float* h     = (float*)alloc((size_t)NN * D * 4);
    float* g     = (float*)alloc((size_t)NN * D * 4);

    zero_kernel<<<(8 * CSTRIDE + 255) / 256, 256, 0, stream>>>(cnt8, 8 * CSTRIDE);
    fused_gemm_count_kernel<<<GEMM_BLOCKS + (NE + 255) / 256, 256, 0, stream>>>(
        x, W1, h, ei, cnt8, rank);
    base_kernel   <<<(NN + 255) / 256, 256, 0, stream>>>(cnt8, cnt);
    scatter_kernel<<<(NE + 255) / 256, 256, 0, stream>>>(ei, ew, rank, cnt8, epack);
    degdinv_kernel<<<(NN + 3) / 4, 256, 0, stream>>>(cnt, epack, dinv);

    agg_kernel <<<(NN + 7) / 8, 256, 0, stream>>>(h, cnt, epack, dinv, b1, g);
    gemm_kernel<<<(NN + 31) / 32, 256, 0, stream>>>(g, W2, h);
    agg_kernel <<<(NN + 7) / 8, 256, 0, stream>>>(h, cnt, epack, dinv, b2, out);
}